// Round 4
// baseline (276.664 us; speedup 1.0000x reference)
//
#include <hip/hip_runtime.h>
#include <math.h>

// CRDLoss on MI355X.
// Phase 0: convert W_s/W_t -> fp16 in ws (1 MB, L2-resident thereafter).
// Phase 1: embed (GEMM 8192x2048x128 + bias + L2 norm) -> fp16 embeddings.
//          R11: NO LDS, NO barriers. Wave-private streaming: each wave owns
//          16 rows x 32 cols; A read fp32->cvt in regs, B halfx8 from L2.
//          512-thread blocks, 32-row tiles, 2 blocks/CU -> 16 waves/CU TLP.
//          (R9/R10's barrier-lockstep 8-wave structure measured 7600 cyc/iter
//          vs the 1600-cyc HBM budget: everything idle at 19% occupancy.)
// Phase 2: 8192x8192 similarity via f16 MFMA; log2-domain epilogue (R10).
// Phase 3: finalize: reduce partials + y histogram -> loss.

typedef _Float16 half_t;
typedef half_t halfx4 __attribute__((ext_vector_type(4)));
typedef half_t halfx8 __attribute__((ext_vector_type(8)));
typedef float f32x4 __attribute__((ext_vector_type(4)));

#define B_TOT   8192
#define K_EMB   2048
#define F_DIM   128
#define INV_T   14.285714285714286f   // 1/0.07
#define EPS_C   0.97f
#define CU_L2   20.60992915555662f    // (1/T) * log2(e)
#define LN2_D   0.6931471805599453
#define LNEPS_D (-0.030459207484708574)  // ln(0.97), double

// hardware transcendentals (2^x, log2 x) without range-conversion muls
__device__ __forceinline__ float fexp2(float x) {
#if __has_builtin(__builtin_amdgcn_exp2f)
    return __builtin_amdgcn_exp2f(x);
#else
    return __expf(x * 0.6931471805599453f);
#endif
}
__device__ __forceinline__ float flog2(float x) {
#if __has_builtin(__builtin_amdgcn_logf)
    return __builtin_amdgcn_logf(x);
#else
    return __logf(x) * 1.4426950408889634f;
#endif
}

// ---------------------------------------------------------------------------
// W fp32 -> fp16.  grid = (256, 2); block = 256; one float4 per thread.
// ---------------------------------------------------------------------------
__global__ __launch_bounds__(256) void cvt_w_kernel(
    const float* __restrict__ Ws, const float* __restrict__ Wt,
    half_t* __restrict__ Ws16, half_t* __restrict__ Wt16)
{
    const float* src = blockIdx.y ? Wt : Ws;
    half_t* dst = blockIdx.y ? Wt16 : Ws16;
    int pos4 = blockIdx.x * 256 + threadIdx.x;      // 0..65535
    float4 v = *(const float4*)(src + (size_t)pos4 * 4);
    halfx4 h4 = {(half_t)v.x, (half_t)v.y, (half_t)v.z, (half_t)v.w};
    *(halfx4*)(dst + (size_t)pos4 * 4) = h4;
}

// ---------------------------------------------------------------------------
// Embed: 32-row tile, 512 threads (8 waves: wr=w&1 row-half, wc=w>>2..0..3
// col-quarter).  Each wave: 16 rows x 32 cols, K streamed in BK=64 steps,
// 2-tile register pipeline, zero LDS in the main loop, zero barriers.
// grid = (256, 2).
// ---------------------------------------------------------------------------
__global__ __launch_bounds__(512, 4) void embed_kernel(
    const float* __restrict__ Xs, const float* __restrict__ Xt,
    const half_t* __restrict__ Ws16, const half_t* __restrict__ Wt16,
    const float* __restrict__ bs, const float* __restrict__ bt,
    half_t* __restrict__ outs, half_t* __restrict__ outt)
{
    const float* X; const half_t* W16; const float* bias; half_t* out;
    if (blockIdx.y == 0) { X = Xs; W16 = Ws16; bias = bs; out = outs; }
    else                 { X = Xt; W16 = Wt16; bias = bt; out = outt; }

    __shared__ float redS[32][4];
    __shared__ float invS[32];

    const int tid  = threadIdx.x;
    const int r0   = blockIdx.x * 32;
    const int lane = tid & 63;
    const int w    = tid >> 6;          // 0..7
    const int wr   = w & 1;             // row half (16 rows)
    const int wc   = w >> 1;            // col quarter (32 cols)
    const int l16  = lane & 15, lhi = lane >> 4;

    float bv0 = bias[wc * 32 + l16];
    float bv1 = bias[wc * 32 + 16 + l16];

    // A fragment source: row (r0 + wr*16 + l16), k base lhi*8 (fp32)
    const float* ap = X + (size_t)(r0 + wr * 16 + l16) * K_EMB + lhi * 8;
    // B fragment sources: W rows (= out cols) wc*32 + l16 (+16), k base lhi*8
    const half_t* bp0 = W16 + (size_t)(wc * 32 + l16) * K_EMB + lhi * 8;
    const half_t* bp1 = bp0 + (size_t)16 * K_EMB;

    f32x4 acc0 = f32x4{0.f, 0.f, 0.f, 0.f};
    f32x4 acc1 = f32x4{0.f, 0.f, 0.f, 0.f};

    // Per tile T (BK=64): kk=0 -> k offset T*64, kk=1 -> T*64+32.
#define LOADT(a0, a1, a2, a3, b00, b01, b10, b11, T) do {                      \
        a0  = *(const float4*)(ap + (size_t)(T) * 64);                         \
        a1  = *(const float4*)(ap + (size_t)(T) * 64 + 4);                     \
        a2  = *(const float4*)(ap + (size_t)(T) * 64 + 32);                    \
        a3  = *(const float4*)(ap + (size_t)(T) * 64 + 36);                    \
        b00 = *(const halfx8*)(bp0 + (size_t)(T) * 64);                        \
        b01 = *(const halfx8*)(bp0 + (size_t)(T) * 64 + 32);                   \
        b10 = *(const halfx8*)(bp1 + (size_t)(T) * 64);                        \
        b11 = *(const halfx8*)(bp1 + (size_t)(T) * 64 + 32);                   \
    } while (0)

#define COMPT(a0, a1, a2, a3, b00, b01, b10, b11) do {                         \
        halfx8 af0 = {(half_t)a0.x, (half_t)a0.y, (half_t)a0.z, (half_t)a0.w, \
                      (half_t)a1.x, (half_t)a1.y, (half_t)a1.z, (half_t)a1.w};\
        halfx8 af1 = {(half_t)a2.x, (half_t)a2.y, (half_t)a2.z, (half_t)a2.w, \
                      (half_t)a3.x, (half_t)a3.y, (half_t)a3.z, (half_t)a3.w};\
        acc0 = __builtin_amdgcn_mfma_f32_16x16x32_f16(af0, b00, acc0, 0, 0, 0);\
        acc1 = __builtin_amdgcn_mfma_f32_16x16x32_f16(af0, b10, acc1, 0, 0, 0);\
        acc0 = __builtin_amdgcn_mfma_f32_16x16x32_f16(af1, b01, acc0, 0, 0, 0);\
        acc1 = __builtin_amdgcn_mfma_f32_16x16x32_f16(af1, b11, acc1, 0, 0, 0);\
    } while (0)

    float4 xa0, xa1, xa2, xa3; halfx8 yb00, yb01, yb10, yb11;   // set A
    float4 za0, za1, za2, za3; halfx8 wb00, wb01, wb10, wb11;   // set B

    LOADT(xa0, xa1, xa2, xa3, yb00, yb01, yb10, yb11, 0);
#pragma unroll 1
    for (int t = 0; t < 30; t += 2) {
        LOADT(za0, za1, za2, za3, wb00, wb01, wb10, wb11, t + 1);
        COMPT(xa0, xa1, xa2, xa3, yb00, yb01, yb10, yb11);
        LOADT(xa0, xa1, xa2, xa3, yb00, yb01, yb10, yb11, t + 2);
        COMPT(za0, za1, za2, za3, wb00, wb01, wb10, wb11);
    }
    LOADT(za0, za1, za2, za3, wb00, wb01, wb10, wb11, 31);
    COMPT(xa0, xa1, xa2, xa3, yb00, yb01, yb10, yb11);
    COMPT(za0, za1, za2, za3, wb00, wb01, wb10, wb11);

#undef LOADT
#undef COMPT

    // epilogue: +bias, row sum-of-squares, normalize, fp16 store.
    // acc row = lhi*4+reg (local rows wr*16 + ...), acc col = l16-indexed.
    float h0[4], h1[4];
    float psum[4];
#pragma unroll
    for (int reg = 0; reg < 4; ++reg) {
        float v0 = acc0[reg] + bv0;
        float v1 = acc1[reg] + bv1;
        h0[reg] = v0; h1[reg] = v1;
        float p = v0 * v0 + v1 * v1;
        p += __shfl_xor(p, 1);
        p += __shfl_xor(p, 2);
        p += __shfl_xor(p, 4);
        p += __shfl_xor(p, 8);
        psum[reg] = p;
    }
    if (l16 == 0)
#pragma unroll
        for (int reg = 0; reg < 4; ++reg)
            redS[wr * 16 + lhi * 4 + reg][wc] = psum[reg];
    __syncthreads();
    if (tid < 32)
        invS[tid] = rsqrtf((redS[tid][0] + redS[tid][1]) +
                           (redS[tid][2] + redS[tid][3]));
    __syncthreads();

#pragma unroll
    for (int reg = 0; reg < 4; ++reg) {
        int row = wr * 16 + lhi * 4 + reg;
        float s = invS[row];
        out[(size_t)(r0 + row) * F_DIM + wc * 32 + l16]      = (half_t)(h0[reg] * s);
        out[(size_t)(r0 + row) * F_DIM + wc * 32 + 16 + l16] = (half_t)(h1[reg] * s);
    }
}

// ---------------------------------------------------------------------------
// Loss: 128x128 tile of fs·ft^T, K=128 in two 64-wide LDS chunks (33 KB LDS).
// grid = (64, 64); block = 256.  (unchanged R10: log2-domain epilogue)
// ---------------------------------------------------------------------------
__global__ __launch_bounds__(256) void loss_kernel(
    const half_t* __restrict__ FS, const half_t* __restrict__ FT,
    const int* __restrict__ y, double* __restrict__ partials)
{
    __shared__ uint4 As4[128 * 8];   // 16 KB
    __shared__ uint4 Bs4[128 * 8];   // 16 KB
    __shared__ int   yrl[128], ycl[128];
    __shared__ float wsum[4];

    const int tid = threadIdx.x;
    const int i0  = blockIdx.x * 128;
    const int j0  = blockIdx.y * 128;

    if (tid < 128) yrl[tid] = y[i0 + tid];
    else           ycl[tid - 128] = y[j0 + tid - 128];

    const int lane = tid & 63;
    const int w    = tid >> 6;
    const int wm   = w >> 1, wn = w & 1;
    const int l16  = lane & 15, lhi = lane >> 4;

#pragma unroll
    for (int i = 0; i < 4; ++i) {
        int f = tid + i * 256;
        int row = f >> 3, c = f & 7;
        As4[row * 8 + (c ^ (row & 7))] = *(const uint4*)(FS + (size_t)(i0 + row) * F_DIM + c * 8);
    }
#pragma unroll
    for (int i = 0; i < 4; ++i) {
        int f = tid + i * 256;
        int row = f >> 3, c = f & 7;
        Bs4[row * 8 + (c ^ (row & 7))] = *(const uint4*)(FT + (size_t)(j0 + row) * F_DIM + c * 8);
    }
    __syncthreads();

    f32x4 acc[4][4];
    for (int im = 0; im < 4; ++im)
        for (int in = 0; in < 4; ++in)
            acc[im][in] = f32x4{0.f, 0.f, 0.f, 0.f};

    for (int kc = 0; kc < 2; ++kc) {
#pragma unroll
        for (int kk = 0; kk < 2; ++kk) {
            halfx8 a[4], b[4];
#pragma unroll
            for (int im = 0; im < 4; ++im) {
                int r = wm * 64 + im * 16 + l16;
                a[im] = *(const halfx8*)&As4[r * 8 + ((kk * 4 + lhi) ^ (r & 7))];
            }
#pragma unroll
            for (int in = 0; in < 4; ++in) {
                int r = wn * 64 + in * 16 + l16;
                b[in] = *(const halfx8*)&Bs4[r * 8 + ((kk * 4 + lhi) ^ (r & 7))];
            }
#pragma unroll
            for (int im = 0; im < 4; ++im)
#pragma unroll
                for (int in = 0; in < 4; ++in)
                    acc[im][in] = __builtin_amdgcn_mfma_f32_16x16x32_f16(
                        a[im], b[in], acc[im][in], 0, 0, 0);
        }
        if (kc == 0) {
            __syncthreads();
#pragma unroll
            for (int i = 0; i < 4; ++i) {
                int f = tid + i * 256;
                int row = f >> 3, c = f & 7;
                As4[row * 8 + (c ^ (row & 7))] =
                    *(const uint4*)(FS + (size_t)(i0 + row) * F_DIM + 64 + c * 8);
            }
#pragma unroll
            for (int i = 0; i < 4; ++i) {
                int f = tid + i * 256;
                int row = f >> 3, c = f & 7;
                Bs4[row * 8 + (c ^ (row & 7))] =
                    *(const uint4*)(FT + (size_t)(j0 + row) * F_DIM + 64 + c * 8);
            }
            __syncthreads();
        }
    }

    // y columns for this thread (4 LDS reads, hoisted)
    int yclv[4];
#pragma unroll
    for (int in = 0; in < 4; ++in) yclv[in] = ycl[wn * 64 + in * 16 + l16];

    float sumL = 0.f, sumU = 0.f;
    if (i0 != j0) {
        // clean path: 6 full-rate + 2 trans per element
#pragma unroll
        for (int im = 0; im < 4; ++im)
#pragma unroll
            for (int reg = 0; reg < 4; ++reg) {
                const int yi = yrl[wm * 64 + im * 16 + lhi * 4 + reg];
#pragma unroll
                for (int in = 0; in < 4; ++in) {
                    float u  = acc[im][in][reg] * CU_L2;
                    float e  = fexp2(u);
                    float l2 = flog2(e + EPS_C);
                    sumL += l2;
                    sumU += (yi == yclv[in]) ? u : 0.f;
                }
            }
    } else {
        // diagonal block: exclude il == jl
#pragma unroll
        for (int im = 0; im < 4; ++im)
#pragma unroll
            for (int reg = 0; reg < 4; ++reg) {
                const int il = wm * 64 + im * 16 + lhi * 4 + reg;
                const int yi = yrl[il];
#pragma unroll
                for (int in = 0; in < 4; ++in) {
                    const int jl = wn * 64 + in * 16 + l16;
                    float u  = acc[im][in][reg] * CU_L2;
                    float e  = fexp2(u);
                    float l2 = flog2(e + EPS_C);
                    bool off = (il != jl);
                    sumL += off ? l2 : 0.f;
                    sumU += (off && yi == yclv[in]) ? u : 0.f;
                }
            }
    }

    float local = sumU - sumL;
    for (int m = 1; m < 64; m <<= 1) local += __shfl_xor(local, m);
    if (lane == 0) wsum[w] = local;
    __syncthreads();
    if (tid == 0)
        partials[blockIdx.y * gridDim.x + blockIdx.x] =
            ((double)wsum[0] + (double)wsum[1]) + ((double)wsum[2] + (double)wsum[3]);
}

// ---------------------------------------------------------------------------
// Finalize: sum partials; y histogram -> N_pos/N_neg;
// loss = -( ln2 * sum + N_neg * ln(eps) ) / B
// ---------------------------------------------------------------------------
__global__ __launch_bounds__(256) void finalize_kernel(
    const double* __restrict__ partials, const int* __restrict__ y,
    float* __restrict__ out)
{
    __shared__ double sh[4];
    __shared__ int hist[128];
    if (threadIdx.x < 128) hist[threadIdx.x] = 0;
    __syncthreads();
    for (int i = threadIdx.x; i < B_TOT; i += 256) atomicAdd(&hist[y[i]], 1);

    double loc = 0.0;
    for (int i = threadIdx.x; i < 4096; i += 256) loc += partials[i];
    for (int m = 1; m < 64; m <<= 1) loc += __shfl_xor(loc, m);
    int lane = threadIdx.x & 63, w = threadIdx.x >> 6;
    if (lane == 0) sh[w] = loc;
    __syncthreads();
    if (threadIdx.x == 0) {
        long long npos = 0;
        for (int c = 0; c < 128; ++c) {
            long long n = hist[c];
            npos += n * n;
        }
        npos -= B_TOT;   // remove diagonal (y_i == y_i)
        long long nneg = (long long)B_TOT * (B_TOT - 1) - npos;
        double total = (sh[0] + sh[1]) + (sh[2] + sh[3]);
        out[0] = (float)(-(LN2_D * total + (double)nneg * LNEPS_D) / (double)B_TOT);
    }
}

// ---------------------------------------------------------------------------
extern "C" void kernel_launch(void* const* d_in, const int* in_sizes, int n_in,
                              void* d_out, int out_size, void* d_ws, size_t ws_size,
                              hipStream_t stream)
{
    // ws layout: [partials 32KB | pad->64KB | fs 2MB | ft 2MB | Ws16 512KB | Wt16 512KB]
    const size_t WS_NEEDED = (64 << 10) + (4 << 20) + (1 << 20);
    if (ws_size < WS_NEEDED) return;   // readable failure instead of OOB fault

    const float* f_s = (const float*)d_in[0];
    const float* f_t = (const float*)d_in[1];
    const int*   y   = (const int*)d_in[2];
    const float* W_s = (const float*)d_in[3];
    const float* b_s = (const float*)d_in[4];
    const float* W_t = (const float*)d_in[5];
    const float* b_t = (const float*)d_in[6];
    float* out = (float*)d_out;

    char* ws = (char*)d_ws;
    double* partials = (double*)ws;                               // 32 KB
    half_t* fs   = (half_t*)(ws + (64 << 10));                    // 2 MB
    half_t* ft   = (half_t*)(ws + (64 << 10) + (2 << 20));        // 2 MB
    half_t* Ws16 = (half_t*)(ws + (64 << 10) + (4 << 20));        // 512 KB
    half_t* Wt16 = (half_t*)(ws + (64 << 10) + (4 << 20) + (512 << 10));

    cvt_w_kernel<<<dim3(256, 2), 256, 0, stream>>>(W_s, W_t, Ws16, Wt16);
    embed_kernel<<<dim3(256, 2), 512, 0, stream>>>(f_s, f_t, Ws16, Wt16, b_s, b_t, fs, ft);
    loss_kernel<<<dim3(64, 64), 256, 0, stream>>>(fs, ft, y, partials);
    finalize_kernel<<<1, 256, 0, stream>>>(partials, y, out);
    (void)in_sizes; (void)n_in; (void)out_size;
}

// Round 5
// 238.850 us; speedup vs baseline: 1.1583x; 1.1583x over previous
//
#include <hip/hip_runtime.h>
#include <math.h>

// CRDLoss on MI355X.
// Phase 0: convert W_s/W_t -> fp16 in ws (1 MB, L2-resident thereafter).
// Phase 1: embed (GEMM 8192x2048x128 + bias + L2 norm) -> fp16 embeddings.
//          R12: 16-row tiles, grid (512,2) -> 4 blocks/CU, 4 waves/block.
//          A staged fp32 via global_load_lds into a 3-deep 24KB LDS ring
//          (prefetch 2 tiles ahead; in-flight bytes >> 9.2KB/CU bandwidth-
//          delay product -- R11's 16B register loads couldn't cover HBM
//          latency at any occupancy).  B read per-wave from L2 (W16 1MB
//          resident).  Counted vmcnt(2) across barriers, never 0.
// Phase 2: 8192x8192 similarity via f16 MFMA; log2-domain epilogue (R10).
// Phase 3: finalize: reduce partials + y histogram -> loss.

typedef _Float16 half_t;
typedef half_t halfx4 __attribute__((ext_vector_type(4)));
typedef half_t halfx8 __attribute__((ext_vector_type(8)));
typedef float f32x4 __attribute__((ext_vector_type(4)));

#define B_TOT   8192
#define K_EMB   2048
#define F_DIM   128
#define INV_T   14.285714285714286f   // 1/0.07
#define EPS_C   0.97f
#define CU_L2   20.60992915555662f    // (1/T) * log2(e)
#define LN2_D   0.6931471805599453
#define LNEPS_D (-0.030459207484708574)  // ln(0.97), double

// hardware transcendentals (2^x, log2 x) without range-conversion muls
__device__ __forceinline__ float fexp2(float x) {
#if __has_builtin(__builtin_amdgcn_exp2f)
    return __builtin_amdgcn_exp2f(x);
#else
    return __expf(x * 0.6931471805599453f);
#endif
}
__device__ __forceinline__ float flog2(float x) {
#if __has_builtin(__builtin_amdgcn_logf)
    return __builtin_amdgcn_logf(x);
#else
    return __logf(x) * 1.4426950408889634f;
#endif
}

// ---------------------------------------------------------------------------
// W fp32 -> fp16.  grid = (256, 2); block = 256; one float4 per thread.
// ---------------------------------------------------------------------------
__global__ __launch_bounds__(256) void cvt_w_kernel(
    const float* __restrict__ Ws, const float* __restrict__ Wt,
    half_t* __restrict__ Ws16, half_t* __restrict__ Wt16)
{
    const float* src = blockIdx.y ? Wt : Ws;
    half_t* dst = blockIdx.y ? Wt16 : Ws16;
    int pos4 = blockIdx.x * 256 + threadIdx.x;      // 0..65535
    float4 v = *(const float4*)(src + (size_t)pos4 * 4);
    halfx4 h4 = {(half_t)v.x, (half_t)v.y, (half_t)v.z, (half_t)v.w};
    *(halfx4*)(dst + (size_t)pos4 * 4) = h4;
}

__device__ __forceinline__ void gload_lds16(const void* g, void* l)
{
    __builtin_amdgcn_global_load_lds(
        (const __attribute__((address_space(1))) void*)g,
        (__attribute__((address_space(3))) void*)l,
        16, 0, 0);
}

// ---------------------------------------------------------------------------
// Embed: 16-row tile x 128 cols, BK=128 (16 k-tiles), 256 threads (4 waves,
// wave w owns cols w*32..w*32+31; all waves share the 16 A rows).
// A: fp32 in LDS ring As[3][16][128] via global_load_lds (2 instrs/wave/tile,
//    1KB each).  16B-quads XOR-swizzled by (row&7): pre-swizzled global
//    source + swizzled ds_read (both-sides rule).
// B: per-wave halfx8 loads straight from W16 (L2-resident).
// grid = (512, 2); 4 blocks/CU.
// ---------------------------------------------------------------------------
__global__ __launch_bounds__(256, 4) void embed_kernel(
    const float* __restrict__ Xs, const float* __restrict__ Xt,
    const half_t* __restrict__ Ws16, const half_t* __restrict__ Wt16,
    const float* __restrict__ bs, const float* __restrict__ bt,
    half_t* __restrict__ outs, half_t* __restrict__ outt)
{
    const float* X; const half_t* W16; const float* bias; half_t* out;
    if (blockIdx.y == 0) { X = Xs; W16 = Ws16; bias = bs; out = outs; }
    else                 { X = Xt; W16 = Wt16; bias = bt; out = outt; }

    __shared__ float As[3][16][128];   // 24 KB ring
    __shared__ float redS[16][4];
    __shared__ float invS[16];

    const int tid  = threadIdx.x;
    const int r0   = blockIdx.x * 16;
    const int lane = tid & 63;
    const int w    = tid >> 6;          // 0..3
    const int l16  = lane & 15, lhi = lane >> 4;

    float bv0 = bias[w * 32 + l16];
    float bv1 = bias[w * 32 + 16 + l16];

    // A gll staging: instr i in {0,1} covers rows w*4 + i*2 + (lane>>5);
    // lane quad q = lane&31 (16B units within the 512B row); source quad is
    // pre-swizzled q ^ (row&7) so the linear LDS write lands swizzled.
    const int arow0 = w * 4 + (lane >> 5);
    const int arow1 = arow0 + 2;
    const float* ag0 = X + (size_t)(r0 + arow0) * K_EMB
                         + (((lane & 31) ^ (arow0 & 7)) << 2);
    const float* ag1 = X + (size_t)(r0 + arow1) * K_EMB
                         + (((lane & 31) ^ (arow1 & 7)) << 2);

    // B fragment pointers: W16 row (= out col) w*32 + cg*16 + l16, k = lhi*8
    const half_t* bp0 = W16 + (size_t)(w * 32 + l16) * K_EMB + lhi * 8;
    const half_t* bp1 = bp0 + (size_t)16 * K_EMB;

    f32x4 acc0 = f32x4{0.f, 0.f, 0.f, 0.f};
    f32x4 acc1 = f32x4{0.f, 0.f, 0.f, 0.f};
    halfx8 b0[4], b1[4];

#define GLL(BUF, T) do {                                                       \
        gload_lds16(ag0 + (size_t)(T) * 128, &As[BUF][w * 4][0]);              \
        gload_lds16(ag1 + (size_t)(T) * 128, &As[BUF][w * 4 + 2][0]);          \
    } while (0)

#define BLOAD(T) do {                                                          \
        _Pragma("unroll")                                                      \
        for (int kk = 0; kk < 4; ++kk) {                                       \
            b0[kk] = *(const halfx8*)(bp0 + (size_t)(T) * 128 + kk * 32);      \
            b1[kk] = *(const halfx8*)(bp1 + (size_t)(T) * 128 + kk * 32);      \
        }                                                                      \
    } while (0)

    // A frag read: row l16, source quads q0 = kk*8 + lhi*2, q0+1; read at
    // swizzled quad (q ^ (l16&7)); cvt 8 fp32 -> halfx8.
#define COMPUTE(BUF) do {                                                      \
        _Pragma("unroll")                                                      \
        for (int kk = 0; kk < 4; ++kk) {                                       \
            const int q0 = kk * 8 + lhi * 2;                                   \
            const int sw = l16 & 7;                                            \
            float4 fa = *(const float4*)&As[BUF][l16][((q0) ^ sw) << 2];       \
            float4 fb = *(const float4*)&As[BUF][l16][((q0 + 1) ^ sw) << 2];   \
            halfx8 af = {(half_t)fa.x, (half_t)fa.y, (half_t)fa.z,             \
                         (half_t)fa.w, (half_t)fb.x, (half_t)fb.y,             \
                         (half_t)fb.z, (half_t)fb.w};                          \
            acc0 = __builtin_amdgcn_mfma_f32_16x16x32_f16(af, b0[kk], acc0, 0, 0, 0); \
            acc1 = __builtin_amdgcn_mfma_f32_16x16x32_f16(af, b1[kk], acc1, 0, 0, 0); \
        }                                                                      \
    } while (0)

    // prologue: tiles 0,1 in flight; wait tile 0 (leave tile 1's 2 instrs)
    GLL(0, 0);
    GLL(1, 1);
    asm volatile("s_waitcnt vmcnt(2)" ::: "memory");
    __builtin_amdgcn_s_barrier();

    // steady state: B(t) issued after gll(t+1) (prev iter) -> consuming B(t)
    // auto-retires gll(t+1); explicit vmcnt(2) leaves only gll(t+2) in
    // flight across the barrier.
#pragma unroll
    for (int t = 0; t < 16; ++t) {
        BLOAD(t);
        if (t < 14) GLL((t + 2) % 3, t + 2);
        COMPUTE(t % 3);
        if (t < 15) {
            asm volatile("s_waitcnt vmcnt(2) lgkmcnt(0)" ::: "memory");
            __builtin_amdgcn_s_barrier();
        }
    }

#undef GLL
#undef BLOAD
#undef COMPUTE

    // epilogue: +bias, row sum-of-squares, normalize, fp16 store.
    // D layout: row = lhi*4+reg, col = w*32 + cg*16 + l16.
    float h0[4], h1[4], psum[4];
#pragma unroll
    for (int reg = 0; reg < 4; ++reg) {
        float v0 = acc0[reg] + bv0;
        float v1 = acc1[reg] + bv1;
        h0[reg] = v0; h1[reg] = v1;
        float p = v0 * v0 + v1 * v1;
        p += __shfl_xor(p, 1);
        p += __shfl_xor(p, 2);
        p += __shfl_xor(p, 4);
        p += __shfl_xor(p, 8);
        psum[reg] = p;
    }
    if (l16 == 0)
#pragma unroll
        for (int reg = 0; reg < 4; ++reg)
            redS[lhi * 4 + reg][w] = psum[reg];
    __syncthreads();
    if (tid < 16)
        invS[tid] = rsqrtf((redS[tid][0] + redS[tid][1]) +
                           (redS[tid][2] + redS[tid][3]));
    __syncthreads();

#pragma unroll
    for (int reg = 0; reg < 4; ++reg) {
        int row = lhi * 4 + reg;
        float s = invS[row];
        out[(size_t)(r0 + row) * F_DIM + w * 32 + l16]      = (half_t)(h0[reg] * s);
        out[(size_t)(r0 + row) * F_DIM + w * 32 + 16 + l16] = (half_t)(h1[reg] * s);
    }
}

// ---------------------------------------------------------------------------
// Loss: 128x128 tile of fs·ft^T, K=128 in two 64-wide LDS chunks (33 KB LDS).
// grid = (64, 64); block = 256.  (unchanged R10: log2-domain epilogue)
// ---------------------------------------------------------------------------
__global__ __launch_bounds__(256) void loss_kernel(
    const half_t* __restrict__ FS, const half_t* __restrict__ FT,
    const int* __restrict__ y, double* __restrict__ partials)
{
    __shared__ uint4 As4[128 * 8];   // 16 KB
    __shared__ uint4 Bs4[128 * 8];   // 16 KB
    __shared__ int   yrl[128], ycl[128];
    __shared__ float wsum[4];

    const int tid = threadIdx.x;
    const int i0  = blockIdx.x * 128;
    const int j0  = blockIdx.y * 128;

    if (tid < 128) yrl[tid] = y[i0 + tid];
    else           ycl[tid - 128] = y[j0 + tid - 128];

    const int lane = tid & 63;
    const int w    = tid >> 6;
    const int wm   = w >> 1, wn = w & 1;
    const int l16  = lane & 15, lhi = lane >> 4;

#pragma unroll
    for (int i = 0; i < 4; ++i) {
        int f = tid + i * 256;
        int row = f >> 3, c = f & 7;
        As4[row * 8 + (c ^ (row & 7))] = *(const uint4*)(FS + (size_t)(i0 + row) * F_DIM + c * 8);
    }
#pragma unroll
    for (int i = 0; i < 4; ++i) {
        int f = tid + i * 256;
        int row = f >> 3, c = f & 7;
        Bs4[row * 8 + (c ^ (row & 7))] = *(const uint4*)(FT + (size_t)(j0 + row) * F_DIM + c * 8);
    }
    __syncthreads();

    f32x4 acc[4][4];
    for (int im = 0; im < 4; ++im)
        for (int in = 0; in < 4; ++in)
            acc[im][in] = f32x4{0.f, 0.f, 0.f, 0.f};

    for (int kc = 0; kc < 2; ++kc) {
#pragma unroll
        for (int kk = 0; kk < 2; ++kk) {
            halfx8 a[4], b[4];
#pragma unroll
            for (int im = 0; im < 4; ++im) {
                int r = wm * 64 + im * 16 + l16;
                a[im] = *(const halfx8*)&As4[r * 8 + ((kk * 4 + lhi) ^ (r & 7))];
            }
#pragma unroll
            for (int in = 0; in < 4; ++in) {
                int r = wn * 64 + in * 16 + l16;
                b[in] = *(const halfx8*)&Bs4[r * 8 + ((kk * 4 + lhi) ^ (r & 7))];
            }
#pragma unroll
            for (int im = 0; im < 4; ++im)
#pragma unroll
                for (int in = 0; in < 4; ++in)
                    acc[im][in] = __builtin_amdgcn_mfma_f32_16x16x32_f16(
                        a[im], b[in], acc[im][in], 0, 0, 0);
        }
        if (kc == 0) {
            __syncthreads();
#pragma unroll
            for (int i = 0; i < 4; ++i) {
                int f = tid + i * 256;
                int row = f >> 3, c = f & 7;
                As4[row * 8 + (c ^ (row & 7))] =
                    *(const uint4*)(FS + (size_t)(i0 + row) * F_DIM + 64 + c * 8);
            }
#pragma unroll
            for (int i = 0; i < 4; ++i) {
                int f = tid + i * 256;
                int row = f >> 3, c = f & 7;
                Bs4[row * 8 + (c ^ (row & 7))] =
                    *(const uint4*)(FT + (size_t)(j0 + row) * F_DIM + 64 + c * 8);
            }
            __syncthreads();
        }
    }

    // y columns for this thread (4 LDS reads, hoisted)
    int yclv[4];
#pragma unroll
    for (int in = 0; in < 4; ++in) yclv[in] = ycl[wn * 64 + in * 16 + l16];

    float sumL = 0.f, sumU = 0.f;
    if (i0 != j0) {
        // clean path: 6 full-rate + 2 trans per element
#pragma unroll
        for (int im = 0; im < 4; ++im)
#pragma unroll
            for (int reg = 0; reg < 4; ++reg) {
                const int yi = yrl[wm * 64 + im * 16 + lhi * 4 + reg];
#pragma unroll
                for (int in = 0; in < 4; ++in) {
                    float u  = acc[im][in][reg] * CU_L2;
                    float e  = fexp2(u);
                    float l2 = flog2(e + EPS_C);
                    sumL += l2;
                    sumU += (yi == yclv[in]) ? u : 0.f;
                }
            }
    } else {
        // diagonal block: exclude il == jl
#pragma unroll
        for (int im = 0; im < 4; ++im)
#pragma unroll
            for (int reg = 0; reg < 4; ++reg) {
                const int il = wm * 64 + im * 16 + lhi * 4 + reg;
                const int yi = yrl[il];
#pragma unroll
                for (int in = 0; in < 4; ++in) {
                    const int jl = wn * 64 + in * 16 + l16;
                    float u  = acc[im][in][reg] * CU_L2;
                    float e  = fexp2(u);
                    float l2 = flog2(e + EPS_C);
                    bool off = (il != jl);
                    sumL += off ? l2 : 0.f;
                    sumU += (off && yi == yclv[in]) ? u : 0.f;
                }
            }
    }

    float local = sumU - sumL;
    for (int m = 1; m < 64; m <<= 1) local += __shfl_xor(local, m);
    if (lane == 0) wsum[w] = local;
    __syncthreads();
    if (tid == 0)
        partials[blockIdx.y * gridDim.x + blockIdx.x] =
            ((double)wsum[0] + (double)wsum[1]) + ((double)wsum[2] + (double)wsum[3]);
}

// ---------------------------------------------------------------------------
// Finalize: sum partials; y histogram -> N_pos/N_neg;
// loss = -( ln2 * sum + N_neg * ln(eps) ) / B
// ---------------------------------------------------------------------------
__global__ __launch_bounds__(256) void finalize_kernel(
    const double* __restrict__ partials, const int* __restrict__ y,
    float* __restrict__ out)
{
    __shared__ double sh[4];
    __shared__ int hist[128];
    if (threadIdx.x < 128) hist[threadIdx.x] = 0;
    __syncthreads();
    for (int i = threadIdx.x; i < B_TOT; i += 256) atomicAdd(&hist[y[i]], 1);

    double loc = 0.0;
    for (int i = threadIdx.x; i < 4096; i += 256) loc += partials[i];
    for (int m = 1; m < 64; m <<= 1) loc += __shfl_xor(loc, m);
    int lane = threadIdx.x & 63, w = threadIdx.x >> 6;
    if (lane == 0) sh[w] = loc;
    __syncthreads();
    if (threadIdx.x == 0) {
        long long npos = 0;
        for (int c = 0; c < 128; ++c) {
            long long n = hist[c];
            npos += n * n;
        }
        npos -= B_TOT;   // remove diagonal (y_i == y_i)
        long long nneg = (long long)B_TOT * (B_TOT - 1) - npos;
        double total = (sh[0] + sh[1]) + (sh[2] + sh[3]);
        out[0] = (float)(-(LN2_D * total + (double)nneg * LNEPS_D) / (double)B_TOT);
    }
}

// ---------------------------------------------------------------------------
extern "C" void kernel_launch(void* const* d_in, const int* in_sizes, int n_in,
                              void* d_out, int out_size, void* d_ws, size_t ws_size,
                              hipStream_t stream)
{
    // ws layout: [partials 32KB | pad->64KB | fs 2MB | ft 2MB | Ws16 512KB | Wt16 512KB]
    const size_t WS_NEEDED = (64 << 10) + (4 << 20) + (1 << 20);
    if (ws_size < WS_NEEDED) return;   // readable failure instead of OOB fault

    const float* f_s = (const float*)d_in[0];
    const float* f_t = (const float*)d_in[1];
    const int*   y   = (const int*)d_in[2];
    const float* W_s = (const float*)d_in[3];
    const float* b_s = (const float*)d_in[4];
    const float* W_t = (const float*)d_in[5];
    const float* b_t = (const float*)d_in[6];
    float* out = (float*)d_out;

    char* ws = (char*)d_ws;
    double* partials = (double*)ws;                               // 32 KB
    half_t* fs   = (half_t*)(ws + (64 << 10));                    // 2 MB
    half_t* ft   = (half_t*)(ws + (64 << 10) + (2 << 20));        // 2 MB
    half_t* Ws16 = (half_t*)(ws + (64 << 10) + (4 << 20));        // 512 KB
    half_t* Wt16 = (half_t*)(ws + (64 << 10) + (4 << 20) + (512 << 10));

    cvt_w_kernel<<<dim3(256, 2), 256, 0, stream>>>(W_s, W_t, Ws16, Wt16);
    embed_kernel<<<dim3(512, 2), 256, 0, stream>>>(f_s, f_t, Ws16, Wt16, b_s, b_t, fs, ft);
    loss_kernel<<<dim3(64, 64), 256, 0, stream>>>(fs, ft, y, partials);
    finalize_kernel<<<1, 256, 0, stream>>>(partials, y, out);
    (void)in_sizes; (void)n_in; (void)out_size;
}

// Round 6
// 203.559 us; speedup vs baseline: 1.3591x; 1.1734x over previous
//
#include <hip/hip_runtime.h>
#include <math.h>

// CRDLoss on MI355X.
// Phase 0: convert W_s/W_t -> fp16 in ws (1 MB, L2-resident thereafter).
// Phase 1: embed (GEMM 8192x2048x128 + bias + L2 norm) -> fp16 embeddings.
//          R13 = R10's proven pipeline (BK=128, 80KB dbuf swizzled LDS,
//          B via global_load_lds, A reg-staged 2 tiles ahead, counted
//          vmcnt never 0) with 8 waves/block (512 thr) instead of 4:
//          16 waves/CU so per-iteration latency tails overlap across waves.
//          (R11/R12 showed: any structure where compute must absorb a
//          same-iteration memory round-trip loses; R10's waits are all on
//          ops issued a full iteration earlier.)
// Phase 2: 8192x8192 similarity via f16 MFMA; log2-domain epilogue (R10).
// Phase 3: finalize: reduce partials + y histogram -> loss.

typedef _Float16 half_t;
typedef half_t halfx4 __attribute__((ext_vector_type(4)));
typedef half_t halfx8 __attribute__((ext_vector_type(8)));
typedef float f32x4 __attribute__((ext_vector_type(4)));

#define B_TOT   8192
#define K_EMB   2048
#define F_DIM   128
#define INV_T   14.285714285714286f   // 1/0.07
#define EPS_C   0.97f
#define CU_L2   20.60992915555662f    // (1/T) * log2(e)
#define LN2_D   0.6931471805599453
#define LNEPS_D (-0.030459207484708574)  // ln(0.97), double

// hardware transcendentals (2^x, log2 x) without range-conversion muls
__device__ __forceinline__ float fexp2(float x) {
#if __has_builtin(__builtin_amdgcn_exp2f)
    return __builtin_amdgcn_exp2f(x);
#else
    return __expf(x * 0.6931471805599453f);
#endif
}
__device__ __forceinline__ float flog2(float x) {
#if __has_builtin(__builtin_amdgcn_logf)
    return __builtin_amdgcn_logf(x);
#else
    return __logf(x) * 1.4426950408889634f;
#endif
}

// ---------------------------------------------------------------------------
// W fp32 -> fp16.  grid = (256, 2); block = 256; one float4 per thread.
// ---------------------------------------------------------------------------
__global__ __launch_bounds__(256) void cvt_w_kernel(
    const float* __restrict__ Ws, const float* __restrict__ Wt,
    half_t* __restrict__ Ws16, half_t* __restrict__ Wt16)
{
    const float* src = blockIdx.y ? Wt : Ws;
    half_t* dst = blockIdx.y ? Wt16 : Ws16;
    int pos4 = blockIdx.x * 256 + threadIdx.x;      // 0..65535
    float4 v = *(const float4*)(src + (size_t)pos4 * 4);
    halfx4 h4 = {(half_t)v.x, (half_t)v.y, (half_t)v.z, (half_t)v.w};
    *(halfx4*)(dst + (size_t)pos4 * 4) = h4;
}

// ---------------------------------------------------------------------------
// Embed helpers
// ---------------------------------------------------------------------------
__device__ __forceinline__ void cvst(uint4* dst, float4 x, float4 y)
{
    halfx8 h = {(half_t)x.x, (half_t)x.y, (half_t)x.z, (half_t)x.w,
                (half_t)y.x, (half_t)y.y, (half_t)y.z, (half_t)y.w};
    *(halfx8*)dst = h;
}

__device__ __forceinline__ void gload_lds16(const void* g, void* l)
{
    __builtin_amdgcn_global_load_lds(
        (const __attribute__((address_space(1))) void*)g,
        (__attribute__((address_space(3))) void*)l,
        16, 0, 0);
}

// ---------------------------------------------------------------------------
// Embed: 32-row tile x all 128 cols, BK=128 (16 k-tiles), 512 threads
// (8 waves: wm=w&1 row-half of 16, wn=w>>1 col-group of 32).
// LDS (uint4 units): [As0 512][As1 512][Bs0 2048][Bs1 2048] = 80 KB -> 2 blk/CU.
// Row = 16 uint4 (128 halves); slot XOR-swizzled by (row & 15).
// Bs[row][slot] = W[row][(slot^(row&15))*8..] (gll linear dest, pre-swizzled
// source); As same relation (swizzled ds_write).
// grid = (256, 2).
// ---------------------------------------------------------------------------
__global__ __launch_bounds__(512, 4) void embed_kernel(
    const float* __restrict__ Xs, const float* __restrict__ Xt,
    const half_t* __restrict__ Ws16, const half_t* __restrict__ Wt16,
    const float* __restrict__ bs, const float* __restrict__ bt,
    half_t* __restrict__ outs, half_t* __restrict__ outt)
{
    const float* X; const half_t* W16; const float* bias; half_t* out;
    if (blockIdx.y == 0) { X = Xs; W16 = Ws16; bias = bs; out = outs; }
    else                 { X = Xt; W16 = Wt16; bias = bt; out = outt; }

    __shared__ uint4 smem[5120];   // exactly 80 KB

    const int tid  = threadIdx.x;
    const int r0   = blockIdx.x * 32;
    const int lane = tid & 63;
    const int w    = tid >> 6;           // 0..7
    const int wm   = w & 1;              // row half (16 rows)
    const int wn   = w >> 1;             // col group (32 cols)
    const int l16  = lane & 15, lhi = lane >> 4;

    float bv0 = bias[wn * 32 + l16];
    float bv1 = bias[wn * 32 + 16 + l16];

    // --- A staging (reg path): 32 rows x 16 uint4; 1 chunk/thread ----------
    const int ar0 = tid >> 4;                 // 0..31
    const int ac  = tid & 15;                 // source slot
    const int axz = ac ^ (ar0 & 15);          // swizzled slot
    const float* aptr = X + (size_t)(r0 + ar0) * K_EMB + ac * 8;

    // --- B staging (global_load_lds): wave w owns rows w*16..w*16+15 --------
    // instr i covers rows w*16+i*4..+3; lane l -> row +(l>>4), linear slot l&15.
    const half_t* bgp[4];
#pragma unroll
    for (int i = 0; i < 4; ++i) {
        int rl = w * 16 + i * 4 + (lane >> 4);
        bgp[i] = W16 + (size_t)rl * K_EMB + (size_t)(((lane & 15) ^ (rl & 15)) * 8);
    }

    f32x4 acc0 = f32x4{0.f, 0.f, 0.f, 0.f};
    f32x4 acc1 = f32x4{0.f, 0.f, 0.f, 0.f};
    float4 aR[2];

#define LOADA(T) do {                                                          \
        aR[0] = *(const float4*)(aptr + (size_t)(T) * 128);                    \
        aR[1] = *(const float4*)(aptr + (size_t)(T) * 128 + 4);                \
    } while (0)

#define CVTA(BUF) cvst(&smem[(BUF) * 512 + ar0 * 16 + axz], aR[0], aR[1])

#define BGLL(BUF, T) do {                                                      \
        _Pragma("unroll")                                                      \
        for (int i = 0; i < 4; ++i)                                            \
            gload_lds16(bgp[i] + (size_t)(T) * 128,                            \
                        &smem[1024 + (BUF) * 2048 + w * 256 + i * 64]);        \
    } while (0)

#define COMPUTE(BUF) do {                                                      \
        _Pragma("unroll")                                                      \
        for (int kk = 0; kk < 4; ++kk) {                                       \
            const int sl = (kk * 4 + lhi) ^ l16;                               \
            halfx8 af  = *(const halfx8*)&smem[(BUF) * 512 +                   \
                                               (wm * 16 + l16) * 16 + sl];     \
            halfx8 b0f = *(const halfx8*)&smem[1024 + (BUF) * 2048 +           \
                                               (wn * 32 + l16) * 16 + sl];     \
            halfx8 b1f = *(const halfx8*)&smem[1024 + (BUF) * 2048 +           \
                                               (wn * 32 + 16 + l16) * 16 + sl];\
            acc0 = __builtin_amdgcn_mfma_f32_16x16x32_f16(af, b0f, acc0, 0, 0, 0); \
            acc1 = __builtin_amdgcn_mfma_f32_16x16x32_f16(af, b1f, acc1, 0, 0, 0); \
        }                                                                      \
    } while (0)

    // ---- prologue: tile0 -> LDS0 (full drain, once); A(1)/B(1) in flight --
    BGLL(0, 0);
    LOADA(0);
    CVTA(0);            // compiler drains vmcnt for A(0) -> also retires B(0)
    LOADA(1);
    BGLL(1, 1);
    asm volatile("s_waitcnt lgkmcnt(0)" ::: "memory");
    __builtin_amdgcn_s_barrier();

    // ---- steady state: 1 barrier/iter, vmcnt never 0 ----------------------
    // invariant at top of iter t: LDS(t&1)=tile t complete; aR=A(t+1) in
    // flight (2); B(t+1) gll in flight (4) into LDS(buf^1).
#pragma unroll 2
    for (int t = 0; t < 14; ++t) {
        const int buf = t & 1;
        COMPUTE(buf);
        CVTA(buf ^ 1);                 // A(t+1): auto vmcnt(4), keeps B(t+1)
        LOADA(t + 2);                  // A(t+2) issue (2 in flight)
        asm volatile("s_waitcnt vmcnt(2) lgkmcnt(0)" ::: "memory");
        __builtin_amdgcn_s_barrier();  // B(t+1)+A(t+1) in LDS; A(t+2) in flight
        BGLL(buf, t + 2);              // safe: all waves done reading buf
    }
    // t = 14
    COMPUTE(0);
    CVTA(1);                           // A(15)
    asm volatile("s_waitcnt vmcnt(0) lgkmcnt(0)" ::: "memory");
    __builtin_amdgcn_s_barrier();
    // t = 15
    COMPUTE(1);

#undef LOADA
#undef CVTA
#undef BGLL
#undef COMPUTE

    // epilogue: +bias, row sum-of-squares, normalize, fp16 store.
    // Reduction scratch aliases As0 (smem[0..511]); waves still finishing
    // COMPUTE(1) only touch As1/Bs1 regions -- disjoint.
    float* redS = (float*)smem;          // [32][4]
    float* invS = ((float*)smem) + 128;  // [32]

    float h0[4], h1[4], psum[4];
#pragma unroll
    for (int reg = 0; reg < 4; ++reg) {
        float v0 = acc0[reg] + bv0;
        float v1 = acc1[reg] + bv1;
        h0[reg] = v0; h1[reg] = v1;
        float p = v0 * v0 + v1 * v1;
        p += __shfl_xor(p, 1);
        p += __shfl_xor(p, 2);
        p += __shfl_xor(p, 4);
        p += __shfl_xor(p, 8);
        psum[reg] = p;
    }
    if (l16 == 0)
#pragma unroll
        for (int reg = 0; reg < 4; ++reg)
            redS[(wm * 16 + lhi * 4 + reg) * 4 + wn] = psum[reg];
    __syncthreads();
    if (tid < 32)
        invS[tid] = rsqrtf((redS[tid * 4] + redS[tid * 4 + 1]) +
                           (redS[tid * 4 + 2] + redS[tid * 4 + 3]));
    __syncthreads();

#pragma unroll
    for (int reg = 0; reg < 4; ++reg) {
        int row = wm * 16 + lhi * 4 + reg;
        float s = invS[row];
        out[(size_t)(r0 + row) * F_DIM + wn * 32 + l16]      = (half_t)(h0[reg] * s);
        out[(size_t)(r0 + row) * F_DIM + wn * 32 + 16 + l16] = (half_t)(h1[reg] * s);
    }
}

// ---------------------------------------------------------------------------
// Loss: 128x128 tile of fs·ft^T, K=128 in two 64-wide LDS chunks (33 KB LDS).
// grid = (64, 64); block = 256.  (unchanged R10: log2-domain epilogue)
// ---------------------------------------------------------------------------
__global__ __launch_bounds__(256) void loss_kernel(
    const half_t* __restrict__ FS, const half_t* __restrict__ FT,
    const int* __restrict__ y, double* __restrict__ partials)
{
    __shared__ uint4 As4[128 * 8];   // 16 KB
    __shared__ uint4 Bs4[128 * 8];   // 16 KB
    __shared__ int   yrl[128], ycl[128];
    __shared__ float wsum[4];

    const int tid = threadIdx.x;
    const int i0  = blockIdx.x * 128;
    const int j0  = blockIdx.y * 128;

    if (tid < 128) yrl[tid] = y[i0 + tid];
    else           ycl[tid - 128] = y[j0 + tid - 128];

    const int lane = tid & 63;
    const int w    = tid >> 6;
    const int wm   = w >> 1, wn = w & 1;
    const int l16  = lane & 15, lhi = lane >> 4;

#pragma unroll
    for (int i = 0; i < 4; ++i) {
        int f = tid + i * 256;
        int row = f >> 3, c = f & 7;
        As4[row * 8 + (c ^ (row & 7))] = *(const uint4*)(FS + (size_t)(i0 + row) * F_DIM + c * 8);
    }
#pragma unroll
    for (int i = 0; i < 4; ++i) {
        int f = tid + i * 256;
        int row = f >> 3, c = f & 7;
        Bs4[row * 8 + (c ^ (row & 7))] = *(const uint4*)(FT + (size_t)(j0 + row) * F_DIM + c * 8);
    }
    __syncthreads();

    f32x4 acc[4][4];
    for (int im = 0; im < 4; ++im)
        for (int in = 0; in < 4; ++in)
            acc[im][in] = f32x4{0.f, 0.f, 0.f, 0.f};

    for (int kc = 0; kc < 2; ++kc) {
#pragma unroll
        for (int kk = 0; kk < 2; ++kk) {
            halfx8 a[4], b[4];
#pragma unroll
            for (int im = 0; im < 4; ++im) {
                int r = wm * 64 + im * 16 + l16;
                a[im] = *(const halfx8*)&As4[r * 8 + ((kk * 4 + lhi) ^ (r & 7))];
            }
#pragma unroll
            for (int in = 0; in < 4; ++in) {
                int r = wn * 64 + in * 16 + l16;
                b[in] = *(const halfx8*)&Bs4[r * 8 + ((kk * 4 + lhi) ^ (r & 7))];
            }
#pragma unroll
            for (int im = 0; im < 4; ++im)
#pragma unroll
                for (int in = 0; in < 4; ++in)
                    acc[im][in] = __builtin_amdgcn_mfma_f32_16x16x32_f16(
                        a[im], b[in], acc[im][in], 0, 0, 0);
        }
        if (kc == 0) {
            __syncthreads();
#pragma unroll
            for (int i = 0; i < 4; ++i) {
                int f = tid + i * 256;
                int row = f >> 3, c = f & 7;
                As4[row * 8 + (c ^ (row & 7))] =
                    *(const uint4*)(FS + (size_t)(i0 + row) * F_DIM + 64 + c * 8);
            }
#pragma unroll
            for (int i = 0; i < 4; ++i) {
                int f = tid + i * 256;
                int row = f >> 3, c = f & 7;
                Bs4[row * 8 + (c ^ (row & 7))] =
                    *(const uint4*)(FT + (size_t)(j0 + row) * F_DIM + 64 + c * 8);
            }
            __syncthreads();
        }
    }

    // y columns for this thread (4 LDS reads, hoisted)
    int yclv[4];
#pragma unroll
    for (int in = 0; in < 4; ++in) yclv[in] = ycl[wn * 64 + in * 16 + l16];

    float sumL = 0.f, sumU = 0.f;
    if (i0 != j0) {
        // clean path: 6 full-rate + 2 trans per element
#pragma unroll
        for (int im = 0; im < 4; ++im)
#pragma unroll
            for (int reg = 0; reg < 4; ++reg) {
                const int yi = yrl[wm * 64 + im * 16 + lhi * 4 + reg];
#pragma unroll
                for (int in = 0; in < 4; ++in) {
                    float u  = acc[im][in][reg] * CU_L2;
                    float e  = fexp2(u);
                    float l2 = flog2(e + EPS_C);
                    sumL += l2;
                    sumU += (yi == yclv[in]) ? u : 0.f;
                }
            }
    } else {
        // diagonal block: exclude il == jl
#pragma unroll
        for (int im = 0; im < 4; ++im)
#pragma unroll
            for (int reg = 0; reg < 4; ++reg) {
                const int il = wm * 64 + im * 16 + lhi * 4 + reg;
                const int yi = yrl[il];
#pragma unroll
                for (int in = 0; in < 4; ++in) {
                    const int jl = wn * 64 + in * 16 + l16;
                    float u  = acc[im][in][reg] * CU_L2;
                    float e  = fexp2(u);
                    float l2 = flog2(e + EPS_C);
                    bool off = (il != jl);
                    sumL += off ? l2 : 0.f;
                    sumU += (off && yi == yclv[in]) ? u : 0.f;
                }
            }
    }

    float local = sumU - sumL;
    for (int m = 1; m < 64; m <<= 1) local += __shfl_xor(local, m);
    if (lane == 0) wsum[w] = local;
    __syncthreads();
    if (tid == 0)
        partials[blockIdx.y * gridDim.x + blockIdx.x] =
            ((double)wsum[0] + (double)wsum[1]) + ((double)wsum[2] + (double)wsum[3]);
}

// ---------------------------------------------------------------------------
// Finalize: sum partials; y histogram -> N_pos/N_neg;
// loss = -( ln2 * sum + N_neg * ln(eps) ) / B
// ---------------------------------------------------------------------------
__global__ __launch_bounds__(256) void finalize_kernel(
    const double* __restrict__ partials, const int* __restrict__ y,
    float* __restrict__ out)
{
    __shared__ double sh[4];
    __shared__ int hist[128];
    if (threadIdx.x < 128) hist[threadIdx.x] = 0;
    __syncthreads();
    for (int i = threadIdx.x; i < B_TOT; i += 256) atomicAdd(&hist[y[i]], 1);

    double loc = 0.0;
    for (int i = threadIdx.x; i < 4096; i += 256) loc += partials[i];
    for (int m = 1; m < 64; m <<= 1) loc += __shfl_xor(loc, m);
    int lane = threadIdx.x & 63, w = threadIdx.x >> 6;
    if (lane == 0) sh[w] = loc;
    __syncthreads();
    if (threadIdx.x == 0) {
        long long npos = 0;
        for (int c = 0; c < 128; ++c) {
            long long n = hist[c];
            npos += n * n;
        }
        npos -= B_TOT;   // remove diagonal (y_i == y_i)
        long long nneg = (long long)B_TOT * (B_TOT - 1) - npos;
        double total = (sh[0] + sh[1]) + (sh[2] + sh[3]);
        out[0] = (float)(-(LN2_D * total + (double)nneg * LNEPS_D) / (double)B_TOT);
    }
}

// ---------------------------------------------------------------------------
extern "C" void kernel_launch(void* const* d_in, const int* in_sizes, int n_in,
                              void* d_out, int out_size, void* d_ws, size_t ws_size,
                              hipStream_t stream)
{
    // ws layout: [partials 32KB | pad->64KB | fs 2MB | ft 2MB | Ws16 512KB | Wt16 512KB]
    const size_t WS_NEEDED = (64 << 10) + (4 << 20) + (1 << 20);
    if (ws_size < WS_NEEDED) return;   // readable failure instead of OOB fault

    const float* f_s = (const float*)d_in[0];
    const float* f_t = (const float*)d_in[1];
    const int*   y   = (const int*)d_in[2];
    const float* W_s = (const float*)d_in[3];
    const float* b_s = (const float*)d_in[4];
    const float* W_t = (const float*)d_in[5];
    const float* b_t = (const float*)d_in[6];
    float* out = (float*)d_out;

    char* ws = (char*)d_ws;
    double* partials = (double*)ws;                               // 32 KB
    half_t* fs   = (half_t*)(ws + (64 << 10));                    // 2 MB
    half_t* ft   = (half_t*)(ws + (64 << 10) + (2 << 20));        // 2 MB
    half_t* Ws16 = (half_t*)(ws + (64 << 10) + (4 << 20));        // 512 KB
    half_t* Wt16 = (half_t*)(ws + (64 << 10) + (4 << 20) + (512 << 10));

    cvt_w_kernel<<<dim3(256, 2), 256, 0, stream>>>(W_s, W_t, Ws16, Wt16);
    embed_kernel<<<dim3(256, 2), 512, 0, stream>>>(f_s, f_t, Ws16, Wt16, b_s, b_t, fs, ft);
    loss_kernel<<<dim3(64, 64), 256, 0, stream>>>(fs, ft, y, partials);
    finalize_kernel<<<1, 256, 0, stream>>>(partials, y, out);
    (void)in_sizes; (void)n_in; (void)out_size;
}